// Round 1
// baseline (480.367 us; speedup 1.0000x reference)
//
#include <hip/hip_runtime.h>

// Problem constants: N=512, BS=64, DIM=256, SIZE=8192
#define T_TOTAL 32768   // N*BS queries
#define D       256
#define K       8192
#define BQ      64      // queries per block tile (2 row-tiles of 32) — shared by all 4 waves
#define KSPLIT  4
#define KSLICE  (K / KSPLIT)
#define NSLICE  (KSPLIT * 4)        // (slice, wn) pairs write disjoint partial slices
#define NCT32   (K / 32)            // 256 code-tiles of 32
#define KT_STRIDE (NCT32 * 64 * 8)  // halves per 16-dim kt slab = 131072
#define NQB     (T_TOTAL / BQ)      // 512 query-blocks

typedef _Float16 half4f   __attribute__((ext_vector_type(4)));
typedef _Float16 half8f   __attribute__((ext_vector_type(8)));
typedef float    floatx16 __attribute__((ext_vector_type(16)));

// d_out scratch: Bhi/Blo after the first PARTIAL_F floats. If ws is big enough,
// partial lives in ws (enables fused reduce+gather); else at d_out head (R12 path).
#define PARTIAL_F 1048576
#define BHALVES   2097152   // halves per B array (16 * 131072) — same footprint as before

__device__ __forceinline__ _Float16 hi16(float x) { return (_Float16)x; }
__device__ __forceinline__ _Float16 lo16(float x, _Float16 h) { return (_Float16)(x - (float)h); }
__device__ __forceinline__ void split4(float4 v, half4f& h, half4f& l) {
    _Float16 hx = hi16(v.x), hy = hi16(v.y), hz = hi16(v.z), hw = hi16(v.w);
    h = (half4f){hx, hy, hz, hw};
    l = (half4f){lo16(v.x, hx), lo16(v.y, hy), lo16(v.z, hz), lo16(v.w, hw)};
}

// ---- kernel 1: fused vocab prep: hv2 (fp32-exact) + fp16 hi/lo 32x32x16-fragment split ----
// 256 blocks, one 32-code tile each. Wave w handles codes 8w..8w+7 (lane = k4 along D).
// Fragment order for mfma_32x32x16_f16 B: lane = col + 32*(k>>3), elem i = k&7, per 16-dim slab.
__global__ void prep_kernel(const float* __restrict__ vocab,
                            _Float16* __restrict__ bhi, _Float16* __restrict__ blo,
                            float* __restrict__ hv2) {
    const int ct = blockIdx.x;           // 32-code tile 0..255
    const int t  = threadIdx.x;
    const int k4 = t & 63;               // float4 index along D
    const int w  = t >> 6;
    const float4* voc4 = (const float4*)vocab;
    const int kt = k4 >> 2;              // 16-dim slab (4 float4 per slab)
    const int q  = k4 & 3;               // float4 within slab
    const int fl = 32 * (q >> 1);        // lane high-half from k-octet
    const int i0 = (q & 1) * 4;          // elem offset within the 8-half fragment
    float ss[8];
    #pragma unroll
    for (int ci = 0; ci < 8; ++ci) {
        int cc = w * 8 + ci;             // code within tile
        float4 v = voc4[(size_t)(ct * 32 + cc) * (D / 4) + k4];
        half4f hh, ll;
        split4(v, hh, ll);
        size_t off = (((size_t)kt * NCT32 + ct) * 64 + (cc + fl)) * 8 + i0;
        *(half4f*)&bhi[off] = hh;
        *(half4f*)&blo[off] = ll;
        ss[ci] = v.x * v.x + v.y * v.y + v.z * v.z + v.w * v.w;
    }
    #pragma unroll
    for (int ci = 0; ci < 8; ++ci) {
        float s = ss[ci];
        #pragma unroll
        for (int off = 32; off; off >>= 1) s += __shfl_down(s, off, 64);
        if ((t & 63) == 0) hv2[ct * 32 + w * 8 + ci] = 0.5f * s;
    }
}

// -------- kernel 2: MFMA argmin; 3-term split; 32x32x16 shape; dual depth-1 pipeline --------
// block 256 = 4 waves; wave wn covers a 64-code quadrant (2 nj tiles of 32); all waves share
// 64 A rows (2 mi tiles of 32). grid 2048 flattened; XCD swizzle locks one K-slice per XCD
// (B slice 2 MB < 4 MB L2). kt2 loop rolled (unroll 1): bounded hoist window (anti-spill).
// Ping-pong on B (global) AND A (LDS). MFMA terms issued term-outer/chain-inner so dependent
// same-acc MFMAs are 4 issues apart (kills chain-serial stalls of the old 16x16 schedule).
__launch_bounds__(256, 2)
__global__ void argmin_kernel(const float* __restrict__ seq,
                              const _Float16* __restrict__ bhi,
                              const _Float16* __restrict__ blo,
                              const float* __restrict__ hv2,
                              float2* __restrict__ partial) {
    // A LDS in fragment order [mi 0..1][kt 0..15][flane 0..63][8], XOR-swizzled by kt<<3
    __shared__ _Float16 AhL[2 * 16 * 64 * 8];   // 32 KB
    __shared__ _Float16 AlL[2 * 16 * 64 * 8];   // 32 KB

    const int t    = threadIdx.x;
    const int lane = t & 63;
    const int wn   = t >> 6;            // code quadrant 0..3
    const int bi   = blockIdx.x;
    const int slice = (bi & 7) >> 1;    // 0..3  (XCD-locked K-slice)
    const int qb    = (bi >> 3) * 2 + (bi & 1);  // 0..511
    const int q0   = qb * BQ;
    const int k0   = slice * KSLICE;

    const float4* seq4 = (const float4*)seq;

    // ---- prologue: split A (64 rows x 256 dims) into fragment-order LDS, once ----
    #pragma unroll
    for (int i = 0; i < 16; ++i) {
        int f   = t + 256 * i;          // 0..4095 float4s
        int row = f >> 6;               // 0..63
        int d4  = f & 63;               // float4 along D
        float4 v = seq4[(size_t)(q0 + row) * (D / 4) + d4];
        half4f h, l;
        split4(v, h, l);
        int kt = d4 >> 2, qq = d4 & 3;
        int off = (((((row >> 5) * 16 + kt) * 64) + ((row & 31) + 32 * (qq >> 1))) * 8
                   + (qq & 1) * 4)
                  ^ (kt << 3);          // swizzle: write conflicts 32-way -> 4-way
        *(half4f*)&AhL[off] = h;
        *(half4f*)&AlL[off] = l;
    }
    __syncthreads();   // the ONLY barrier

    float best[32];
    int   bidx[32];
    #pragma unroll
    for (int b = 0; b < 32; ++b) { best[b] = 3.4e38f; bidx[b] = 0; }

    const _Float16* bh_l = bhi + (size_t)lane * 8;
    const _Float16* bl_l = blo + (size_t)lane * 8;

    for (int c0i = 0; c0i < KSLICE / 256; ++c0i) {   // 8 c0 tiles of 256 codes
        const int c0  = k0 + c0i * 256;
        const int ct0 = (c0 >> 5) + wn * 2;          // this wave's 2 code-tiles of 32
        const size_t cb = (size_t)ct0 * 512;

        floatx16 acc[2][2];
        #pragma unroll
        for (int mi = 0; mi < 2; ++mi)
            #pragma unroll
            for (int nj = 0; nj < 2; ++nj)
                #pragma unroll
                for (int r = 0; r < 16; ++r) acc[mi][nj][r] = 0.0f;

        // ping-pong buffers: B (global) and A (LDS)
        half8f bh0[2], bl0[2], bh1[2], bl1[2];
        half8f ah0[2], al0[2], ah1[2], al1[2];
        #pragma unroll
        for (int nj = 0; nj < 2; ++nj) {          // preload kt=0
            bh0[nj] = *(const half8f*)&bh_l[cb + nj * 512];
            bl0[nj] = *(const half8f*)&bl_l[cb + nj * 512];
        }
        #pragma unroll
        for (int mi = 0; mi < 2; ++mi) {
            const int ao = ((mi * 16) * 64 + lane) * 8;   // kt=0: swizzle term is 0
            ah0[mi] = *(const half8f*)&AhL[ao];
            al0[mi] = *(const half8f*)&AlL[ao];
        }

        #pragma unroll 1   // REAL loop: bounded hoist window (anti-spill)
        for (int kt2 = 0; kt2 < 8; ++kt2) {
            const int kt = kt2 * 2;
            // prefetch kt+1: B -> buf1, A -> areg1 (both overlap kt's MFMA burst)
            {
                const size_t kb = (size_t)(kt + 1) * KT_STRIDE + cb;
                #pragma unroll
                for (int nj = 0; nj < 2; ++nj) {
                    bh1[nj] = *(const half8f*)&bh_l[kb + nj * 512];
                    bl1[nj] = *(const half8f*)&bl_l[kb + nj * 512];
                }
                #pragma unroll
                for (int mi = 0; mi < 2; ++mi) {
                    const int ao = (((mi * 16 + kt + 1) * 64 + lane) * 8) ^ ((kt + 1) << 3);
                    ah1[mi] = *(const half8f*)&AhL[ao];
                    al1[mi] = *(const half8f*)&AlL[ao];
                }
            }
            // MFMA kt (buf0): 3-term Markidis (ll dropped, err ~2e-6 << gaps),
            // term-outer so the 3 dependent MFMAs per chain are 4 issues apart
            #pragma unroll
            for (int nj = 0; nj < 2; ++nj)
                #pragma unroll
                for (int mi = 0; mi < 2; ++mi)
                    acc[mi][nj] = __builtin_amdgcn_mfma_f32_32x32x16_f16(al0[mi], bh0[nj], acc[mi][nj], 0, 0, 0);
            #pragma unroll
            for (int nj = 0; nj < 2; ++nj)
                #pragma unroll
                for (int mi = 0; mi < 2; ++mi)
                    acc[mi][nj] = __builtin_amdgcn_mfma_f32_32x32x16_f16(ah0[mi], bl0[nj], acc[mi][nj], 0, 0, 0);
            #pragma unroll
            for (int nj = 0; nj < 2; ++nj)
                #pragma unroll
                for (int mi = 0; mi < 2; ++mi)
                    acc[mi][nj] = __builtin_amdgcn_mfma_f32_32x32x16_f16(ah0[mi], bh0[nj], acc[mi][nj], 0, 0, 0);
            // prefetch kt+2 into buf0/areg0 (uniform branch; skipped on last lap)
            if (kt2 < 7) {
                const size_t kb = (size_t)(kt + 2) * KT_STRIDE + cb;
                #pragma unroll
                for (int nj = 0; nj < 2; ++nj) {
                    bh0[nj] = *(const half8f*)&bh_l[kb + nj * 512];
                    bl0[nj] = *(const half8f*)&bl_l[kb + nj * 512];
                }
                #pragma unroll
                for (int mi = 0; mi < 2; ++mi) {
                    const int ao = (((mi * 16 + kt + 2) * 64 + lane) * 8) ^ ((kt + 2) << 3);
                    ah0[mi] = *(const half8f*)&AhL[ao];
                    al0[mi] = *(const half8f*)&AlL[ao];
                }
            }
            // MFMA kt+1 (buf1)
            #pragma unroll
            for (int nj = 0; nj < 2; ++nj)
                #pragma unroll
                for (int mi = 0; mi < 2; ++mi)
                    acc[mi][nj] = __builtin_amdgcn_mfma_f32_32x32x16_f16(al1[mi], bh1[nj], acc[mi][nj], 0, 0, 0);
            #pragma unroll
            for (int nj = 0; nj < 2; ++nj)
                #pragma unroll
                for (int mi = 0; mi < 2; ++mi)
                    acc[mi][nj] = __builtin_amdgcn_mfma_f32_32x32x16_f16(ah1[mi], bl1[nj], acc[mi][nj], 0, 0, 0);
            #pragma unroll
            for (int nj = 0; nj < 2; ++nj)
                #pragma unroll
                for (int mi = 0; mi < 2; ++mi)
                    acc[mi][nj] = __builtin_amdgcn_mfma_f32_32x32x16_f16(ah1[mi], bh1[nj], acc[mi][nj], 0, 0, 0);
        }

        // epilogue: s = 0.5*|v|^2 - dot; running first-argmin (ascending c per lane).
        // C/D layout (32x32, HW-measured): col = lane&31, row = (r&3) + 8*(r>>2) + 4*(lane>>5)
        #pragma unroll
        for (int nj = 0; nj < 2; ++nj) {
            int c = c0 + (wn * 2 + nj) * 32 + (lane & 31);
            float hv = hv2[c];
            #pragma unroll
            for (int mi = 0; mi < 2; ++mi)
                #pragma unroll
                for (int r = 0; r < 16; ++r) {
                    float s = hv - acc[mi][nj][r];
                    int b = mi * 16 + r;
                    if (s < best[b]) { best[b] = s; bidx[b] = c; }
                }
        }
    }

    // reduce across the 32 col-lanes (same rows within each lane-half; xor<32 keeps lane>>5)
    #pragma unroll
    for (int off = 1; off < 32; off <<= 1) {
        #pragma unroll
        for (int b = 0; b < 32; ++b) {
            float ob = __shfl_xor(best[b], off, 64);
            int   oi = __shfl_xor(bidx[b], off, 64);
            if (ob < best[b] || (ob == best[b] && oi < bidx[b])) {
                best[b] = ob; bidx[b] = oi;
            }
        }
    }
    if ((lane & 31) == 0) {
        const size_t sl = (size_t)(slice * 4 + wn) * T_TOTAL;  // disjoint per (slice, wn)
        const int rowadd = (lane >> 5) * 4;
        #pragma unroll
        for (int mi = 0; mi < 2; ++mi)
            #pragma unroll
            for (int r = 0; r < 16; ++r) {
                int qr = q0 + mi * 32 + (r & 3) + 8 * (r >> 2) + rowadd;
                partial[sl + qr] = make_float2(best[mi * 16 + r], (float)bidx[mi * 16 + r]);
            }
    }
}

// ---- kernel 3a (fused, needs partial in ws): fold 16 slices + gather, wave per row ----
__global__ void redgather_kernel(const float* __restrict__ vocab,
                                 const float2* __restrict__ partial,
                                 float* __restrict__ out) {
    int r    = blockIdx.x * 4 + (threadIdx.x >> 6);
    int lane = threadIdx.x & 63;
    float bm = 3.4e38f;
    int   bi = 0x7fffffff;
    if (lane < 16) {
        float2 p = partial[(size_t)lane * T_TOTAL + r];
        bm = p.x; bi = (int)p.y;
    }
    #pragma unroll
    for (int off = 1; off < 16; off <<= 1) {   // xor<16 stays within the 16-lane group
        float ob = __shfl_xor(bm, off, 64);
        int   oi = __shfl_xor(bi, off, 64);
        if (ob < bm || (ob == bm && oi < bi)) { bm = ob; bi = oi; }
    }
    int k = __shfl(bi, 0, 64);                 // lanes 0-15 hold the true min; take lane 0
    const float4* src = (const float4*)(vocab + (size_t)k * D);
    float4*       dst = (float4*)(out + (size_t)r * D);
    dst[lane] = src[lane];
    if (lane == 0) out[(size_t)T_TOTAL * D + r] = (float)k;
}

// ---- kernel 3b/4b (fallback path, partial at d_out head): separate reduce + gather ----
__global__ void reduce_kernel(const float2* __restrict__ partial, int* __restrict__ idx) {
    int q = blockIdx.x * 256 + threadIdx.x;
    float bm = 3.4e38f;
    int   bi = 0x7fffffff;
    #pragma unroll
    for (int s = 0; s < NSLICE; ++s) {
        float2 p = partial[(size_t)s * T_TOTAL + q];
        int pi = (int)p.y;
        if (p.x < bm || (p.x == bm && pi < bi)) { bm = p.x; bi = pi; }
    }
    idx[q] = bi;
}

__global__ void gather_kernel(const float* __restrict__ vocab,
                              const int* __restrict__ idx,
                              float* __restrict__ out) {
    int r    = blockIdx.x * 4 + (threadIdx.x >> 6);
    int lane = threadIdx.x & 63;
    int k = idx[r];
    const float4* src = (const float4*)(vocab + (size_t)k * D);
    float4*       dst = (float4*)(out + (size_t)r * D);
    dst[lane] = src[lane];
    if (lane == 0) out[(size_t)T_TOTAL * D + r] = (float)k;
}

extern "C" void kernel_launch(void* const* d_in, const int* in_sizes, int n_in,
                              void* d_out, int out_size, void* d_ws, size_t ws_size,
                              hipStream_t stream) {
    const float* seq   = (const float*)d_in[0];   // [T, D] f32
    const float* vocab = (const float*)d_in[1];   // [K, D] f32
    float* out = (float*)d_out;

    float* hv2 = (float*)d_ws;                               // K floats
    _Float16* bhi = (_Float16*)(out + PARTIAL_F);            // 4 MB (d_out scratch)
    _Float16* blo = bhi + BHALVES;                           // 4 MB

    // partial placement: ws if it fits (enables fused reduce+gather — no cross-kernel
    // race since gather never writes ws), else d_out head (R12 2-kernel path).
    const size_t need_ws = (size_t)(K + 2 * NSLICE * T_TOTAL) * sizeof(float) + 256;
    const bool fused = ws_size >= need_ws;

    hipLaunchKernelGGL(prep_kernel, dim3(NCT32), dim3(256), 0, stream, vocab, bhi, blo, hv2);

    if (fused) {
        float2* partial = (float2*)(hv2 + K);                // in ws
        hipLaunchKernelGGL(argmin_kernel,    dim3(NQB * KSPLIT), dim3(256), 0, stream,
                           seq, bhi, blo, hv2, partial);
        hipLaunchKernelGGL(redgather_kernel, dim3(T_TOTAL / 4),  dim3(256), 0, stream,
                           vocab, partial, out);
    } else {
        float2* partial = (float2*)d_out;                    // at d_out head
        int* idx = (int*)(hv2 + K);                          // T ints in ws
        hipLaunchKernelGGL(argmin_kernel, dim3(NQB * KSPLIT), dim3(256), 0, stream,
                           seq, bhi, blo, hv2, partial);
        hipLaunchKernelGGL(reduce_kernel, dim3(T_TOTAL / 256), dim3(256), 0, stream, partial, idx);
        hipLaunchKernelGGL(gather_kernel, dim3(T_TOTAL / 4),   dim3(256), 0, stream, vocab, idx, out);
    }
}